// Round 5
// baseline (172.874 us; speedup 1.0000x reference)
//
#include <hip/hip_runtime.h>
#include <stdint.h>

typedef _Float16 f16;
typedef _Float16 f16x8 __attribute__((ext_vector_type(8)));
typedef _Float16 f16x4 __attribute__((ext_vector_type(4)));
typedef _Float16 f16x2 __attribute__((ext_vector_type(2)));
typedef float f32x4 __attribute__((ext_vector_type(4)));

#define MROWS 8192
#define KDIM 512
#define NSEQ 1024
#define NH 8

__device__ __forceinline__ void gload16(void* lds, const void* g) {
  __builtin_amdgcn_global_load_lds(
      (const __attribute__((address_space(1))) unsigned*)g,
      (__attribute__((address_space(3))) unsigned*)lds, 16, 0, 0);
}

__device__ __forceinline__ f32x4 mfma16(f16x8 a, f16x8 b, f32x4 c) {
  return __builtin_amdgcn_mfma_f32_16x16x32_f16(a, b, c, 0, 0, 0);
}

// Vt slot swizzle: bijective on {0..7} within every aligned 8-lane group for
// BOTH the gload staging walk (d = base+l>>3, s = l&7) and the PV b128 read
// (d = dj*16 + lrow). sg(d) = ((d>>1)&7) ^ ((d&1)<<2).
__device__ __forceinline__ int vsg(int d) {
  return ((d >> 1) & 7) ^ ((d & 1) << 2);
}

// ---------------------------------------------------------------------------
// fp32 -> f16 convert of x, w_qkv, w_proj
// ---------------------------------------------------------------------------
__global__ __launch_bounds__(256) void cvt_kernel(
    const float* __restrict__ x, const float* __restrict__ wq,
    const float* __restrict__ wp, f16* __restrict__ x16,
    f16* __restrict__ wq16, f16* __restrict__ wp16) {
  int t = blockIdx.x * 256 + threadIdx.x;
  int stride = gridDim.x * 256;
  for (int i = t; i < (MROWS * KDIM) / 4; i += stride) {
    float4 v = ((const float4*)x)[i];
    f16x4 o = {(f16)v.x, (f16)v.y, (f16)v.z, (f16)v.w};
    ((f16x4*)x16)[i] = o;
  }
  for (int i = t; i < (3 * KDIM * KDIM) / 4; i += stride) {
    float4 v = ((const float4*)wq)[i];
    f16x4 o = {(f16)v.x, (f16)v.y, (f16)v.z, (f16)v.w};
    ((f16x4*)wq16)[i] = o;
  }
  for (int i = t; i < (KDIM * KDIM) / 4; i += stride) {
    float4 v = ((const float4*)wp)[i];
    f16x4 o = {(f16)v.x, (f16)v.y, (f16)v.z, (f16)v.w};
    ((f16x4*)wp16)[i] = o;
  }
}

// ---------------------------------------------------------------------------
// Double-buffered NT-GEMM main loop: C[128x128], BK=64, 256 threads (4 waves),
// wave = one 64x64 quadrant = 4x4 grid of 16x16x32 f16 MFMAs.
// Counted vmcnt(8) keeps next tile's global_load_lds in flight across the raw
// s_barrier. (Same race analysis as round 4 — measured correct.)
// ---------------------------------------------------------------------------
__device__ __forceinline__ void gemm_mainloop_db(
    const f16* __restrict__ A, const f16* __restrict__ B, int m0, int n0,
    f16* As0, f16* As1, f16* Bs0, f16* Bs1, f32x4 (&acc)[4][4]) {
  const int tid = threadIdx.x;
  const int w = tid >> 6, l = tid & 63;
  const int wr = w >> 1, wc = w & 1;
  const int lrow = l & 15, lk = l >> 4;
  const int srow = l >> 3, sslot = l & 7;
  const int scol = ((sslot ^ srow) << 3);  // pre-swizzled source col
  const int NT = KDIM / 64;

  auto STAGE = [&](int bb, int kb) {
    f16* Ad = bb ? As1 : As0;
    f16* Bd = bb ? Bs1 : Bs0;
#pragma unroll
    for (int j = 0; j < 4; ++j) {
      int i = w * 4 + j;
      int row = i * 8 + srow;
      gload16(Ad + i * 512, A + (size_t)(m0 + row) * KDIM + kb + scol);
      gload16(Bd + i * 512, B + (size_t)(n0 + row) * KDIM + kb + scol);
    }
  };

  STAGE(0, 0);
#pragma unroll 1
  for (int t = 0; t < NT; ++t) {
    if (t + 1 < NT) {
      STAGE((t + 1) & 1, (t + 1) * 64);
      asm volatile("s_waitcnt vmcnt(8)" ::: "memory");
    } else {
      asm volatile("s_waitcnt vmcnt(0)" ::: "memory");
    }
    __builtin_amdgcn_s_barrier();  // bar1: buf[t&1] fully staged
    const f16* Asr = (t & 1) ? As1 : As0;
    const f16* Bsr = (t & 1) ? Bs1 : Bs0;
#pragma unroll
    for (int kk = 0; kk < 2; ++kk) {
      int slotbase = kk * 4 + lk;
      f16x8 af[4], bf[4];
#pragma unroll
      for (int mi = 0; mi < 4; ++mi) {
        int row = wr * 64 + mi * 16 + lrow;
        af[mi] = *(const f16x8*)(Asr + row * 64 + ((slotbase ^ (row & 7)) << 3));
      }
#pragma unroll
      for (int nj = 0; nj < 4; ++nj) {
        int row = wc * 64 + nj * 16 + lrow;
        bf[nj] = *(const f16x8*)(Bsr + row * 64 + ((slotbase ^ (row & 7)) << 3));
      }
#pragma unroll
      for (int mi = 0; mi < 4; ++mi)
#pragma unroll
        for (int nj = 0; nj < 4; ++nj)
          acc[mi][nj] = mfma16(af[mi], bf[nj], acc[mi][nj]);
    }
    __builtin_amdgcn_s_barrier();  // bar2: reads of buf[t&1] done
  }
}

// ---------------------------------------------------------------------------
// qkv = x16 @ wq16^T. Q,K scattered as f16 [b][h][n][64]; V scattered
// TRANSPOSED as v16T [b][h][d][n] so attention can stage it with
// global_load_lds directly into the swizzled Vt layout (no LDS transpose).
// ---------------------------------------------------------------------------
__global__ __launch_bounds__(256, 2) void qkv_gemm(
    const f16* __restrict__ x16, const f16* __restrict__ wq16,
    f16* __restrict__ q16, f16* __restrict__ k16, f16* __restrict__ v16T) {
  __shared__ f16 As0[128 * 64], As1[128 * 64];
  __shared__ f16 Bs0[128 * 64], Bs1[128 * 64];
  f32x4 acc[4][4];
#pragma unroll
  for (int i = 0; i < 4; ++i)
#pragma unroll
    for (int j = 0; j < 4; ++j) acc[i][j] = (f32x4){0.f, 0.f, 0.f, 0.f};

  const int m0 = blockIdx.y * 128, n0 = blockIdx.x * 128;
  gemm_mainloop_db(x16, wq16, m0, n0, As0, As1, Bs0, Bs1, acc);

  const int tid = threadIdx.x;
  const int w = tid >> 6, l = tid & 63;
  const int wr = w >> 1, wc = w & 1;
#pragma unroll
  for (int mi = 0; mi < 4; ++mi) {
#pragma unroll
    for (int rr = 0; rr < 4; ++rr) {
      int m = m0 + wr * 64 + mi * 16 + (l >> 4) * 4 + rr;
      int b = m >> 10, n = m & 1023;
#pragma unroll
      for (int nj = 0; nj < 4; ++nj) {
        int d = n0 + wc * 64 + nj * 16 + (l & 15);
        int which = d >> 9, c = d & 511;
        int h = c >> 6, dd = c & 63;
        f16 val = (f16)acc[mi][nj][rr];
        size_t hb = (size_t)(b * NH + h);
        if (which == 0)
          q16[(hb * NSEQ + n) * 64 + dd] = val;
        else if (which == 1)
          k16[(hb * NSEQ + n) * 64 + dd] = val;
        else
          v16T[(hb * 64 + dd) * NSEQ + n] = val;  // transposed store
      }
    }
  }
}

// ---------------------------------------------------------------------------
// out = a16 @ wp16^T (fp32 out).
// ---------------------------------------------------------------------------
__global__ __launch_bounds__(256, 2) void proj_gemm(
    const f16* __restrict__ a16, const f16* __restrict__ wp16,
    float* __restrict__ out) {
  __shared__ f16 As0[128 * 64], As1[128 * 64];
  __shared__ f16 Bs0[128 * 64], Bs1[128 * 64];
  f32x4 acc[4][4];
#pragma unroll
  for (int i = 0; i < 4; ++i)
#pragma unroll
    for (int j = 0; j < 4; ++j) acc[i][j] = (f32x4){0.f, 0.f, 0.f, 0.f};

  const int m0 = blockIdx.y * 128, n0 = blockIdx.x * 128;
  gemm_mainloop_db(a16, wp16, m0, n0, As0, As1, Bs0, Bs1, acc);

  const int tid = threadIdx.x;
  const int w = tid >> 6, l = tid & 63;
  const int wr = w >> 1, wc = w & 1;
#pragma unroll
  for (int mi = 0; mi < 4; ++mi) {
#pragma unroll
    for (int rr = 0; rr < 4; ++rr) {
      int m = m0 + wr * 64 + mi * 16 + (l >> 4) * 4 + rr;
#pragma unroll
      for (int nj = 0; nj < 4; ++nj) {
        int d = n0 + wc * 64 + nj * 16 + (l & 15);
        out[(size_t)m * KDIM + d] = acc[mi][nj][rr];
      }
    }
  }
}

// ---------------------------------------------------------------------------
// MFMA flash attention v3: swapped QK^T, in-register P, no LDS writes at all.
// Block = 64 q-rows x (b,h); 256 thr = 4 waves x 16 q-rows. Grid 1024 = 4/CU.
// LDS = Ks{0,1} + Vt{0,1} = 32 KB.  K staged row-major+XOR-swizzle; V staged
// from pre-transposed global v16T straight into swizzled Vt[d][kv] (source
// pre-swizzle, LDS walk linear).  P moves S^T-layout -> PV-A-layout via 16
// __shfl + 8 selects (quarter-wave exchange), so there is NO Ps buffer and
// NO lgkm-drained barrier.
// Barriers (2/tile, no drains):
//   bar_a: all waves finished compute(t-1) -> safe to overwrite buf[cur^1]
//   STAGE(t+1 -> cur^1); vmcnt(4) == own stage(t) landed
//   bar_b: everyone's stage(t) landed -> compute(t) from buf[cur]
// ---------------------------------------------------------------------------
__global__ __launch_bounds__(256, 4) void attn_f16(
    const f16* __restrict__ q16, const f16* __restrict__ k16,
    const f16* __restrict__ v16T, const float* __restrict__ log_decay,
    f16* __restrict__ aout) {
  __shared__ f16 Ks0[64 * 64], Ks1[64 * 64];
  __shared__ f16 Vt0[64 * 64], Vt1[64 * 64];

  const int tid = threadIdx.x;
  const int w = tid >> 6, l = tid & 63;
  const int lrow = l & 15, lk = l >> 4;
  const int srow = l >> 3, sslot = l & 7;
  const int q0 = blockIdx.x * 64;
  const int h = blockIdx.y, b = blockIdx.z;
  const size_t kbase = ((size_t)(b * NH + h)) * NSEQ * 64;  // q16/k16 [n][64]
  const size_t vbase = ((size_t)(b * NH + h)) * 64 * NSEQ;  // v16T [64][n]

  const float decay = log1pf(__expf(log_decay[h]));  // softplus

  // Q fragments (B-operand), pre-scaled by hd^-0.5
  f16x8 qf[2];
#pragma unroll
  for (int kk = 0; kk < 2; ++kk) {
    int row = q0 + w * 16 + lrow;
    f16x8 v = *(const f16x8*)(q16 + kbase + (size_t)row * 64 + kk * 32 + lk * 8);
#pragma unroll
    for (int e = 0; e < 8; ++e) v[e] = v[e] * (f16)0.125f;
    qf[kk] = v;
  }

  const int qn = q0 + w * 16 + lrow;
  const int qr = qn >> 5, qc = qn & 31;

  f32x4 O[4];
#pragma unroll
  for (int dj = 0; dj < 4; ++dj) O[dj] = (f32x4){0.f, 0.f, 0.f, 0.f};
  float mrow = -1e30f, lsum = 0.f;

  auto STAGE = [&](int bb, int c0) {
    f16* Kd = bb ? Ks1 : Ks0;
    f16* Vd = bb ? Vt1 : Vt0;
#pragma unroll
    for (int j = 0; j < 2; ++j) {
      int i = w * 2 + j;
      int krow = i * 8 + srow;
      gload16(Kd + i * 512,
              k16 + kbase + (size_t)(c0 + krow) * 64 + ((sslot ^ (krow & 7)) << 3));
      int d = i * 8 + srow;  // Vt row
      gload16(Vd + i * 512,
              v16T + vbase + (size_t)d * NSEQ + c0 + ((sslot ^ vsg(d)) << 3));
    }
  };

  const int srcA = lrow + ((l >> 4) & 1) * 32;  // P-exchange source lanes
  const int srcB = srcA + 16;
  const int msel = lk >> 1;

  STAGE(0, 0);
#pragma unroll 1
  for (int t = 0; t < NSEQ / 64; ++t) {
    const int c0 = t * 64;
    const int cur = t & 1;
    __builtin_amdgcn_s_barrier();  // bar_a
    if (t + 1 < NSEQ / 64) {
      STAGE(cur ^ 1, c0 + 64);
      asm volatile("s_waitcnt vmcnt(4)" ::: "memory");
    } else {
      asm volatile("s_waitcnt vmcnt(0)" ::: "memory");
    }
    __builtin_amdgcn_s_barrier();  // bar_b
    const f16* Kc = cur ? Ks1 : Ks0;
    const f16* Vc = cur ? Vt1 : Vt0;

    // ---- S^T = K @ Q^T (8 MFMA): lane holds S[kv = c0+mi*16+lk*4+rr][q=lrow]
    f32x4 s[4];
#pragma unroll
    for (int mi = 0; mi < 4; ++mi) s[mi] = (f32x4){0.f, 0.f, 0.f, 0.f};
#pragma unroll
    for (int kk = 0; kk < 2; ++kk) {
#pragma unroll
      for (int mi = 0; mi < 4; ++mi) {
        int row = mi * 16 + lrow;
        f16x8 kf = *(const f16x8*)(Kc + row * 64 + (((kk * 4 + lk) ^ (row & 7)) << 3));
        s[mi] = mfma16(kf, qf[kk], s[mi]);
      }
    }

    // ---- bias + online softmax (in-register)
    float mx = -1e30f;
#pragma unroll
    for (int mi = 0; mi < 4; ++mi) {
      int kvb = c0 + mi * 16 + lk * 4;
      int krb = kvb >> 5, kcb = kvb & 31;
      float dr = (float)__builtin_abs(qr - krb);
      int t1 = qc - kcb;
#pragma unroll
      for (int rr = 0; rr < 4; ++rr) {
        float dc = (float)__builtin_abs(t1 - rr);
        float tt = fmaf(-decay, dr + dc, s[mi][rr]);
        s[mi][rr] = tt;
        mx = fmaxf(mx, tt);
      }
    }
    mx = fmaxf(mx, __shfl_xor(mx, 16));
    mx = fmaxf(mx, __shfl_xor(mx, 32));
    float mnew = fmaxf(mrow, mx);
    float al = __expf(mrow - mnew);
    mrow = mnew;
    float rs = 0.f;
    unsigned wpk[4][2];  // f16x2-packed P, wpk[mi][j] = (p[2j], p[2j+1])
#pragma unroll
    for (int mi = 0; mi < 4; ++mi) {
#pragma unroll
      for (int j = 0; j < 2; ++j) {
        float p0 = __expf(s[mi][2 * j] - mnew);
        float p1 = __expf(s[mi][2 * j + 1] - mnew);
        rs += p0 + p1;
        union { f16x2 h; unsigned u; } pk;
        pk.h = (f16x2){(f16)p0, (f16)p1};
        wpk[mi][j] = pk.u;
      }
    }
    rs += __shfl_xor(rs, 16);
    rs += __shfl_xor(rs, 32);
    lsum = lsum * al + rs;

    // ---- rescale O (alpha uniform across lk at lane lrow=q; O rows at lk*4+rr)
#pragma unroll
    for (int rr = 0; rr < 4; ++rr) {
      float a = __shfl(al, lk * 4 + rr);
#pragma unroll
      for (int dj = 0; dj < 4; ++dj) O[dj][rr] *= a;
    }

    // ---- P exchange (S^T layout -> PV A layout) + PV (8 MFMA)
#pragma unroll
    for (int kk = 0; kk < 2; ++kk) {
      unsigned paw[4];
      {
        int a0 = __shfl((int)wpk[kk * 2][0], srcA);
        int b0 = __shfl((int)wpk[kk * 2 + 1][0], srcA);
        paw[0] = (unsigned)(msel ? b0 : a0);
        int a1 = __shfl((int)wpk[kk * 2][1], srcA);
        int b1 = __shfl((int)wpk[kk * 2 + 1][1], srcA);
        paw[1] = (unsigned)(msel ? b1 : a1);
        int a2 = __shfl((int)wpk[kk * 2][0], srcB);
        int b2 = __shfl((int)wpk[kk * 2 + 1][0], srcB);
        paw[2] = (unsigned)(msel ? b2 : a2);
        int a3 = __shfl((int)wpk[kk * 2][1], srcB);
        int b3 = __shfl((int)wpk[kk * 2 + 1][1], srcB);
        paw[3] = (unsigned)(msel ? b3 : a3);
      }
      union { unsigned u[4]; f16x8 v; } pc;
      pc.u[0] = paw[0]; pc.u[1] = paw[1]; pc.u[2] = paw[2]; pc.u[3] = paw[3];
      f16x8 pa = pc.v;
#pragma unroll
      for (int dj = 0; dj < 4; ++dj) {
        int d = dj * 16 + lrow;
        f16x8 vb = *(const f16x8*)(Vc + d * 64 + (((kk * 4 + lk) ^ vsg(d)) << 3));
        O[dj] = mfma16(pa, vb, O[dj]);
      }
    }
  }

  // ---- epilogue: normalize, write aout [b*1024+n][h*64+d] as f16
  float linv = 1.f / lsum;
#pragma unroll
  for (int rr = 0; rr < 4; ++rr) {
    float inv = __shfl(linv, lk * 4 + rr);
    int q = q0 + w * 16 + lk * 4 + rr;
    size_t rowbase = ((size_t)(b * NSEQ + q)) * KDIM + h * 64;
#pragma unroll
    for (int dj = 0; dj < 4; ++dj)
      aout[rowbase + dj * 16 + lrow] = (f16)(O[dj][rr] * inv);
  }
}

extern "C" void kernel_launch(void* const* d_in, const int* in_sizes, int n_in,
                              void* d_out, int out_size, void* d_ws, size_t ws_size,
                              hipStream_t stream) {
  const float* x = (const float*)d_in[0];
  const float* w_qkv = (const float*)d_in[1];
  const float* w_proj = (const float*)d_in[2];
  const float* log_decay = (const float*)d_in[3];

  f16* ws = (f16*)d_ws;
  f16* x16 = ws;
  f16* wq16 = x16 + (size_t)MROWS * KDIM;
  f16* wp16 = wq16 + (size_t)3 * KDIM * KDIM;
  f16* q16 = wp16 + (size_t)KDIM * KDIM;
  f16* k16 = q16 + (size_t)MROWS * KDIM;
  f16* v16T = k16 + (size_t)MROWS * KDIM;
  f16* a16 = v16T + (size_t)MROWS * KDIM;

  cvt_kernel<<<1024, 256, 0, stream>>>(x, w_qkv, w_proj, x16, wq16, wp16);
  qkv_gemm<<<dim3(12, 64), 256, 0, stream>>>(x16, wq16, q16, k16, v16T);
  attn_f16<<<dim3(16, NH, 8), 256, 0, stream>>>(q16, k16, v16T, log_decay, a16);
  proj_gemm<<<dim3(4, 64), 256, 0, stream>>>(a16, wp16, (float*)d_out);
}

// Round 6
// 146.381 us; speedup vs baseline: 1.1810x; 1.1810x over previous
//
#include <hip/hip_runtime.h>
#include <stdint.h>

typedef _Float16 f16;
typedef _Float16 f16x8 __attribute__((ext_vector_type(8)));
typedef _Float16 f16x4 __attribute__((ext_vector_type(4)));
typedef float f32x4 __attribute__((ext_vector_type(4)));

#define MROWS 8192
#define KDIM 512
#define NSEQ 1024
#define NH 8

__device__ __forceinline__ void gload16(void* lds, const void* g) {
  __builtin_amdgcn_global_load_lds(
      (const __attribute__((address_space(1))) unsigned*)g,
      (__attribute__((address_space(3))) unsigned*)lds, 16, 0, 0);
}

__device__ __forceinline__ f32x4 mfma16(f16x8 a, f16x8 b, f32x4 c) {
  return __builtin_amdgcn_mfma_f32_16x16x32_f16(a, b, c, 0, 0, 0);
}

// Vt slot swizzle (bijective on {0..7} per 8-lane group on both stage walk
// and PV b128 read).
__device__ __forceinline__ int vsg(int d) {
  return ((d >> 1) & 7) ^ ((d & 1) << 2);
}

// ---------------------------------------------------------------------------
// fp32 -> f16 convert of x, w_qkv, w_proj
// ---------------------------------------------------------------------------
__global__ __launch_bounds__(256) void cvt_kernel(
    const float* __restrict__ x, const float* __restrict__ wq,
    const float* __restrict__ wp, f16* __restrict__ x16,
    f16* __restrict__ wq16, f16* __restrict__ wp16) {
  int t = blockIdx.x * 256 + threadIdx.x;
  int stride = gridDim.x * 256;
  for (int i = t; i < (MROWS * KDIM) / 4; i += stride) {
    float4 v = ((const float4*)x)[i];
    f16x4 o = {(f16)v.x, (f16)v.y, (f16)v.z, (f16)v.w};
    ((f16x4*)x16)[i] = o;
  }
  for (int i = t; i < (3 * KDIM * KDIM) / 4; i += stride) {
    float4 v = ((const float4*)wq)[i];
    f16x4 o = {(f16)v.x, (f16)v.y, (f16)v.z, (f16)v.w};
    ((f16x4*)wq16)[i] = o;
  }
  for (int i = t; i < (KDIM * KDIM) / 4; i += stride) {
    float4 v = ((const float4*)wp)[i];
    f16x4 o = {(f16)v.x, (f16)v.y, (f16)v.z, (f16)v.w};
    ((f16x4*)wp16)[i] = o;
  }
}

// ---------------------------------------------------------------------------
// Double-buffered NT-GEMM main loop (measured-good since round 2).
// ---------------------------------------------------------------------------
__device__ __forceinline__ void gemm_mainloop_db(
    const f16* __restrict__ A, const f16* __restrict__ B, int m0, int n0,
    f16* As0, f16* As1, f16* Bs0, f16* Bs1, f32x4 (&acc)[4][4]) {
  const int tid = threadIdx.x;
  const int w = tid >> 6, l = tid & 63;
  const int wr = w >> 1, wc = w & 1;
  const int lrow = l & 15, lk = l >> 4;
  const int srow = l >> 3, sslot = l & 7;
  const int scol = ((sslot ^ srow) << 3);
  const int NT = KDIM / 64;

  auto STAGE = [&](int bb, int kb) {
    f16* Ad = bb ? As1 : As0;
    f16* Bd = bb ? Bs1 : Bs0;
#pragma unroll
    for (int j = 0; j < 4; ++j) {
      int i = w * 4 + j;
      int row = i * 8 + srow;
      gload16(Ad + i * 512, A + (size_t)(m0 + row) * KDIM + kb + scol);
      gload16(Bd + i * 512, B + (size_t)(n0 + row) * KDIM + kb + scol);
    }
  };

  STAGE(0, 0);
#pragma unroll 1
  for (int t = 0; t < NT; ++t) {
    if (t + 1 < NT) {
      STAGE((t + 1) & 1, (t + 1) * 64);
      asm volatile("s_waitcnt vmcnt(8)" ::: "memory");
    } else {
      asm volatile("s_waitcnt vmcnt(0)" ::: "memory");
    }
    __builtin_amdgcn_s_barrier();
    const f16* Asr = (t & 1) ? As1 : As0;
    const f16* Bsr = (t & 1) ? Bs1 : Bs0;
#pragma unroll
    for (int kk = 0; kk < 2; ++kk) {
      int slotbase = kk * 4 + lk;
      f16x8 af[4], bf[4];
#pragma unroll
      for (int mi = 0; mi < 4; ++mi) {
        int row = wr * 64 + mi * 16 + lrow;
        af[mi] = *(const f16x8*)(Asr + row * 64 + ((slotbase ^ (row & 7)) << 3));
      }
#pragma unroll
      for (int nj = 0; nj < 4; ++nj) {
        int row = wc * 64 + nj * 16 + lrow;
        bf[nj] = *(const f16x8*)(Bsr + row * 64 + ((slotbase ^ (row & 7)) << 3));
      }
#pragma unroll
      for (int mi = 0; mi < 4; ++mi)
#pragma unroll
        for (int nj = 0; nj < 4; ++nj)
          acc[mi][nj] = mfma16(af[mi], bf[nj], acc[mi][nj]);
    }
    __builtin_amdgcn_s_barrier();
  }
}

// ---------------------------------------------------------------------------
// qkv = x16 @ wq16^T. Q,K scattered as f16 [b][h][n][64]. V blocks
// (n0 >= 1024) transpose their 128(d) x 128(m) quadrant through LDS and store
// coalesced f16x8 rows into v16T [b][h][d][n].
// ---------------------------------------------------------------------------
__global__ __launch_bounds__(256, 2) void qkv_gemm(
    const f16* __restrict__ x16, const f16* __restrict__ wq16,
    f16* __restrict__ q16, f16* __restrict__ k16, f16* __restrict__ v16T) {
  __shared__ f16 SMEM[4 * 128 * 64];  // 64 KB, carved below
  f16* As0 = SMEM;
  f16* As1 = SMEM + 8192;
  f16* Bs0 = SMEM + 16384;
  f16* Bs1 = SMEM + 24576;

  f32x4 acc[4][4];
#pragma unroll
  for (int i = 0; i < 4; ++i)
#pragma unroll
    for (int j = 0; j < 4; ++j) acc[i][j] = (f32x4){0.f, 0.f, 0.f, 0.f};

  const int m0 = blockIdx.y * 128, n0 = blockIdx.x * 128;
  gemm_mainloop_db(x16, wq16, m0, n0, As0, As1, Bs0, Bs1, acc);

  const int tid = threadIdx.x;
  const int w = tid >> 6, l = tid & 63;
  const int wr = w >> 1, wc = w & 1;
  const int lrow = l & 15, lk = l >> 4;

  if (n0 < 1024) {
    // ---- Q/K blocks: element scatter (row-major targets, measured fine)
#pragma unroll
    for (int mi = 0; mi < 4; ++mi) {
#pragma unroll
      for (int rr = 0; rr < 4; ++rr) {
        int m = m0 + wr * 64 + mi * 16 + lk * 4 + rr;
        int b = m >> 10, n = m & 1023;
#pragma unroll
        for (int nj = 0; nj < 4; ++nj) {
          int d = n0 + wc * 64 + nj * 16 + lrow;
          int which = d >> 9, c = d & 511;
          int h = c >> 6, dd = c & 63;
          f16 val = (f16)acc[mi][nj][rr];
          size_t hb = (size_t)(b * NH + h);
          if (which == 0)
            q16[(hb * NSEQ + n) * 64 + dd] = val;
          else
            k16[(hb * NSEQ + n) * 64 + dd] = val;
        }
      }
    }
  } else {
    // ---- V block: LDS transpose (stride 136 pad -> 2-way max conflicts)
    f16* T = SMEM;  // 128 x 136 f16 = 34.8 KB, mainloop done with SMEM
#pragma unroll
    for (int mi = 0; mi < 4; ++mi) {
#pragma unroll
      for (int nj = 0; nj < 4; ++nj) {
        int dloc = wc * 64 + nj * 16 + lrow;
        int nloc = wr * 64 + mi * 16 + lk * 4;
        f16x4 pw = {(f16)acc[mi][nj][0], (f16)acc[mi][nj][1],
                    (f16)acc[mi][nj][2], (f16)acc[mi][nj][3]};
        *(f16x4*)(T + dloc * 136 + nloc) = pw;
      }
    }
    __syncthreads();
    const int b = m0 >> 10;
    const int nbase = m0 & 1023;
#pragma unroll
    for (int rs = 0; rs < 8; ++rs) {
      int dloc = w * 32 + rs * 4 + (l >> 4);
      int ncol = (l & 15) * 8;
      f16x8 vv = *(const f16x8*)(T + dloc * 136 + ncol);
      int c = (n0 + dloc) & 511;
      int hh = c >> 6, dd = c & 63;
      size_t hb = (size_t)(b * NH + hh);
      *(f16x8*)(v16T + (hb * 64 + dd) * NSEQ + nbase + ncol) = vv;
    }
  }
}

// ---------------------------------------------------------------------------
// out = a16 @ wp16^T (fp32 out).
// ---------------------------------------------------------------------------
__global__ __launch_bounds__(256, 2) void proj_gemm(
    const f16* __restrict__ a16, const f16* __restrict__ wp16,
    float* __restrict__ out) {
  __shared__ f16 As0[128 * 64], As1[128 * 64];
  __shared__ f16 Bs0[128 * 64], Bs1[128 * 64];
  f32x4 acc[4][4];
#pragma unroll
  for (int i = 0; i < 4; ++i)
#pragma unroll
    for (int j = 0; j < 4; ++j) acc[i][j] = (f32x4){0.f, 0.f, 0.f, 0.f};

  const int m0 = blockIdx.y * 128, n0 = blockIdx.x * 128;
  gemm_mainloop_db(a16, wp16, m0, n0, As0, As1, Bs0, Bs1, acc);

  const int tid = threadIdx.x;
  const int w = tid >> 6, l = tid & 63;
  const int wr = w >> 1, wc = w & 1;
#pragma unroll
  for (int mi = 0; mi < 4; ++mi) {
#pragma unroll
    for (int rr = 0; rr < 4; ++rr) {
      int m = m0 + wr * 64 + mi * 16 + (l >> 4) * 4 + rr;
#pragma unroll
      for (int nj = 0; nj < 4; ++nj) {
        int d = n0 + wc * 64 + nj * 16 + (l & 15);
        out[(size_t)m * KDIM + d] = acc[mi][nj][rr];
      }
    }
  }
}

// ---------------------------------------------------------------------------
// MFMA flash attention v4: round-4 shape (128q, 4 waves x 32q, njq=2,
// swapped QK^T, Ps through LDS) with:
//  - XCD-aware block mapping: all 8 q-blocks of one (b,h) on one XCD so K/V
//    (256 KB/pair, 2 MB/XCD) stay L2-resident.
//  - Vt staged directly from pre-transposed v16T (no Vs, no LDS transpose).
//  - tile-invariant bias dc hoisted to registers; per tile only 2 dr values.
//  - Ks/Vt/Ps all double-buffered; 2 barriers/tile:
//      vmcnt(0); bar1;          // STAGE(t) landed; all t-1 readers done
//      STAGE(t+1) -> buf[c^1];  // overlaps QK^T+softmax below
//      QK^T(t) from Ks[c]; softmax -> Ps[c];
//      lgkmcnt(0); bar2;        // Ps visible
//      PV(t) from Ps[c], Vt[c];
//    Race audit: STAGE(t+1) writes buf[c^1]; its readers (QK^T/PV of t-1)
//    are all before bar1(t). Staged loads drain at bar1(t+1), a full tile
//    later. Ps WAR safe via dbuf.
// ---------------------------------------------------------------------------
__global__ __launch_bounds__(256, 2) void attn_f16(
    const f16* __restrict__ q16, const f16* __restrict__ k16,
    const f16* __restrict__ v16T, const float* __restrict__ log_decay,
    f16* __restrict__ aout) {
  __shared__ f16 Ks0[64 * 64], Ks1[64 * 64];
  __shared__ f16 Vt0[64 * 64], Vt1[64 * 64];
  __shared__ f16 Ps0[128 * 64], Ps1[128 * 64];

  const int tid = threadIdx.x;
  const int w = tid >> 6, l = tid & 63;
  const int lrow = l & 15, lk = l >> 4;
  const int srow = l >> 3, sslot = l & 7;

  // XCD-aware decode: blocks with the same (b,h) share L%8 -> same XCD.
  const int L = blockIdx.x;
  const int pair = (L & 7) * 8 + ((L >> 3) & 7);
  const int q0 = (L >> 6) * 128;
  const int b = pair >> 3, h = pair & 7;

  const size_t kbase = ((size_t)(b * NH + h)) * NSEQ * 64;  // q16/k16 [n][64]
  const size_t vbase = ((size_t)(b * NH + h)) * 64 * NSEQ;  // v16T [64][n]

  const float decay = log1pf(__expf(log_decay[h]));  // softplus
  const float negdecay = -decay;

  // Q fragments (B-operand), pre-scaled by hd^-0.5
  f16x8 qf[2][2];
#pragma unroll
  for (int njq = 0; njq < 2; ++njq)
#pragma unroll
    for (int kk = 0; kk < 2; ++kk) {
      int row = q0 + w * 32 + njq * 16 + lrow;
      f16x8 v = *(const f16x8*)(q16 + kbase + (size_t)row * 64 + kk * 32 + lk * 8);
#pragma unroll
      for (int e = 0; e < 8; ++e) v[e] = v[e] * (f16)0.125f;
      qf[njq][kk] = v;
    }

  int qr_[2], qc_[2];
#pragma unroll
  for (int njq = 0; njq < 2; ++njq) {
    int qn = q0 + w * 32 + njq * 16 + lrow;
    qr_[njq] = qn >> 5;
    qc_[njq] = qn & 31;
  }

  // Tile-invariant bias part: bdc[njq][mi][rr] = -decay * |qc - kc|,
  // kc = (mi*16 + lk*4 + rr) & 31  (c0 is a multiple of 64).
  float bdc[2][4][4];
#pragma unroll
  for (int njq = 0; njq < 2; ++njq)
#pragma unroll
    for (int mi = 0; mi < 4; ++mi)
#pragma unroll
      for (int rr = 0; rr < 4; ++rr) {
        int kc = (mi * 16 + lk * 4 + rr) & 31;
        int da = qc_[njq] - kc;
        da = (da < 0) ? -da : da;
        bdc[njq][mi][rr] = negdecay * (float)da;
      }

  f32x4 O[2][4];
#pragma unroll
  for (int njq = 0; njq < 2; ++njq)
#pragma unroll
    for (int dj = 0; dj < 4; ++dj) O[njq][dj] = (f32x4){0.f, 0.f, 0.f, 0.f};
  float mrow[2] = {-1e30f, -1e30f}, lsum[2] = {0.f, 0.f};

  auto STAGE = [&](int bb, int cc0) {
    f16* Kd = bb ? Ks1 : Ks0;
    f16* Vd = bb ? Vt1 : Vt0;
#pragma unroll
    for (int j = 0; j < 2; ++j) {
      int i = w * 2 + j;
      int row = i * 8 + srow;  // K row / Vt d-row, 0..63
      gload16(Kd + i * 512,
              k16 + kbase + (size_t)(cc0 + row) * 64 + ((sslot ^ (row & 7)) << 3));
      gload16(Vd + i * 512,
              v16T + vbase + (size_t)row * NSEQ + cc0 + ((sslot ^ vsg(row)) << 3));
    }
  };

  STAGE(0, 0);
#pragma unroll 1
  for (int t = 0; t < NSEQ / 64; ++t) {
    const int c0 = t * 64;
    const int cur = t & 1;
    asm volatile("s_waitcnt vmcnt(0)" ::: "memory");
    __builtin_amdgcn_s_barrier();  // bar1
    if (t + 1 < NSEQ / 64) STAGE(cur ^ 1, c0 + 64);

    const f16* Kc = cur ? Ks1 : Ks0;
    const f16* Vc = cur ? Vt1 : Vt0;
    f16* Psc = cur ? Ps1 : Ps0;

    // ---- S^T = K @ Q^T (16 MFMA, kf amortized over njq)
    f32x4 s[4][2];
#pragma unroll
    for (int mi = 0; mi < 4; ++mi)
#pragma unroll
      for (int njq = 0; njq < 2; ++njq) s[mi][njq] = (f32x4){0.f, 0.f, 0.f, 0.f};
#pragma unroll
    for (int kk = 0; kk < 2; ++kk) {
#pragma unroll
      for (int mi = 0; mi < 4; ++mi) {
        int row = mi * 16 + lrow;
        f16x8 kf = *(const f16x8*)(Kc + row * 64 + (((kk * 4 + lk) ^ (row & 7)) << 3));
#pragma unroll
        for (int njq = 0; njq < 2; ++njq)
          s[mi][njq] = mfma16(kf, qf[njq][kk], s[mi][njq]);
      }
    }

    // ---- per-tile dr bias (kr = 2t + (mi>>1))
    float bdr[2][2];
#pragma unroll
    for (int njq = 0; njq < 2; ++njq) {
      int d0 = qr_[njq] - 2 * t;
      int a0 = (d0 < 0) ? -d0 : d0;
      int d1 = d0 - 1;
      int a1 = (d1 < 0) ? -d1 : d1;
      bdr[njq][0] = negdecay * (float)a0;
      bdr[njq][1] = negdecay * (float)a1;
    }

    // ---- bias + online softmax; P -> Ps[cur] (b64 writes)
    float al[2];
#pragma unroll
    for (int njq = 0; njq < 2; ++njq) {
      float mx = -1e30f;
#pragma unroll
      for (int mi = 0; mi < 4; ++mi) {
        float bdrm = bdr[njq][mi >> 1];
#pragma unroll
        for (int rr = 0; rr < 4; ++rr) {
          float tt = s[mi][njq][rr] + (bdc[njq][mi][rr] + bdrm);
          s[mi][njq][rr] = tt;
          mx = fmaxf(mx, tt);
        }
      }
      mx = fmaxf(mx, __shfl_xor(mx, 16));
      mx = fmaxf(mx, __shfl_xor(mx, 32));
      float mnew = fmaxf(mrow[njq], mx);
      al[njq] = __expf(mrow[njq] - mnew);
      mrow[njq] = mnew;
      float rs = 0.f;
      int qq = w * 32 + njq * 16 + lrow;
#pragma unroll
      for (int mi = 0; mi < 4; ++mi) {
        f16x4 pw;
#pragma unroll
        for (int rr = 0; rr < 4; ++rr) {
          float p = __expf(s[mi][njq][rr] - mnew);
          rs += p;
          pw[rr] = (f16)p;
        }
        int slot = mi * 2 + (lk >> 1);
        *(f16x4*)(Psc + qq * 64 + ((slot ^ (qq & 7)) << 3) + ((lk & 1) << 2)) = pw;
      }
      rs += __shfl_xor(rs, 16);
      rs += __shfl_xor(rs, 32);
      lsum[njq] = lsum[njq] * al[njq] + rs;
    }

    // ---- rescale O (alpha at lane lrow=q -> O rows lk*4+rr)
#pragma unroll
    for (int njq = 0; njq < 2; ++njq) {
#pragma unroll
      for (int rr = 0; rr < 4; ++rr) {
        float a = __shfl(al[njq], lk * 4 + rr);
#pragma unroll
        for (int dj = 0; dj < 4; ++dj) O[njq][dj][rr] *= a;
      }
    }

    asm volatile("s_waitcnt lgkmcnt(0)" ::: "memory");
    __builtin_amdgcn_s_barrier();  // bar2: Ps visible

    // ---- O += P @ V (16 MFMA)
#pragma unroll
    for (int kk = 0; kk < 2; ++kk) {
      int slotbase = kk * 4 + lk;
      f16x8 pa[2], vb[4];
#pragma unroll
      for (int njq = 0; njq < 2; ++njq) {
        int row = w * 32 + njq * 16 + lrow;
        pa[njq] = *(const f16x8*)(Psc + row * 64 + ((slotbase ^ (row & 7)) << 3));
      }
#pragma unroll
      for (int dj = 0; dj < 4; ++dj) {
        int d = dj * 16 + lrow;
        vb[dj] = *(const f16x8*)(Vc + d * 64 + ((slotbase ^ vsg(d)) << 3));
      }
#pragma unroll
      for (int njq = 0; njq < 2; ++njq)
#pragma unroll
        for (int dj = 0; dj < 4; ++dj)
          O[njq][dj] = mfma16(pa[njq], vb[dj], O[njq][dj]);
    }
  }

  // ---- epilogue: normalize, write aout [b*1024+n][h*64+d] as f16
  float linv[2] = {1.f / lsum[0], 1.f / lsum[1]};
#pragma unroll
  for (int njq = 0; njq < 2; ++njq) {
#pragma unroll
    for (int rr = 0; rr < 4; ++rr) {
      float inv = __shfl(linv[njq], lk * 4 + rr);
      int qn = q0 + w * 32 + njq * 16 + lk * 4 + rr;
      size_t rowbase = ((size_t)(b * NSEQ + qn)) * KDIM + h * 64;
#pragma unroll
      for (int dj = 0; dj < 4; ++dj)
        aout[rowbase + dj * 16 + lrow] = (f16)(O[njq][dj][rr] * inv);
    }
  }
}

extern "C" void kernel_launch(void* const* d_in, const int* in_sizes, int n_in,
                              void* d_out, int out_size, void* d_ws, size_t ws_size,
                              hipStream_t stream) {
  const float* x = (const float*)d_in[0];
  const float* w_qkv = (const float*)d_in[1];
  const float* w_proj = (const float*)d_in[2];
  const float* log_decay = (const float*)d_in[3];

  f16* ws = (f16*)d_ws;
  f16* x16 = ws;
  f16* wq16 = x16 + (size_t)MROWS * KDIM;
  f16* wp16 = wq16 + (size_t)3 * KDIM * KDIM;
  f16* q16 = wp16 + (size_t)KDIM * KDIM;
  f16* k16 = q16 + (size_t)MROWS * KDIM;
  f16* v16T = k16 + (size_t)MROWS * KDIM;
  f16* a16 = v16T + (size_t)MROWS * KDIM;

  cvt_kernel<<<1024, 256, 0, stream>>>(x, w_qkv, w_proj, x16, wq16, wp16);
  qkv_gemm<<<dim3(12, 64), 256, 0, stream>>>(x16, wq16, q16, k16, v16T);
  attn_f16<<<dim3(512), 256, 0, stream>>>(q16, k16, v16T, log_decay, a16);
  proj_gemm<<<dim3(4, 64), 256, 0, stream>>>(a16, wp16, (float*)d_out);
}